// Round 3
// baseline (18.748 us; speedup 1.0000x reference)
//
#include <hip/hip_runtime.h>
#include <math.h>

// DescriptorMatcher via split-bf16 MFMA, b=1, c=64, N=1024.
//   out[i,j,o]  = sum_c v1[i,c]*v2[j,c]*W[o,c] + bias[o]   (3 GEMMs: B in {v2, v2*w0, v2*w1})
//   onorm[i,j]  = sqrt(s1[i] + s2[j] - 2*dot(i,j)*r1[i]*r2[j])
// prep_kernel: fp32 [c][n] inputs -> row-major bf16 hi/lo panels [n][128] in ws
//              (4 arrays: v1, v2d, v2w0, v2w1) + norm scalars s/r per row.
// match_kernel: per 64-thread block, one wave computes a 32x16 output tile with
//              36 mfma_f32_16x16x32_bf16 (hi*hi + hi*lo + lo*hi per K-half),
//              fragments loaded straight from L2-resident ws (no LDS, no barrier).

#define CDIM 64
#define EPSN 1e-6f

typedef float        f4 __attribute__((ext_vector_type(4)));
typedef float        f2 __attribute__((ext_vector_type(2)));
typedef short        s8 __attribute__((ext_vector_type(8)));
typedef unsigned int u32;
typedef u32          u4 __attribute__((ext_vector_type(4)));

__device__ __forceinline__ unsigned short bf16_rne(float x) {
    u32 u = __float_as_uint(x);
    u32 r = u + 0x7fffu + ((u >> 16) & 1u);
    return (unsigned short)(r >> 16);
}

// ---------------- pre-pass: convert + scale + split + norm scalars ----------
__global__ __launch_bounds__(256)
void prep_kernel(const float* __restrict__ g1, const float* __restrict__ g2,
                 const float* __restrict__ W,
                 unsigned short* __restrict__ ws_bf, float* __restrict__ ws_sc,
                 int N) {
    const int b = blockIdx.x, t = threadIdx.x;
    if (b < 32) {
        // task = arr*2048 + khalf*1024 + row ; arr,khalf uniform per block
        const int task  = b * 256 + t;
        const int arr   = task >> 11;          // 0:v1  1:v2  2:v2*w0  3:v2*w1
        const int khalf = (task >> 10) & 1;
        const int row   = task & 1023;
        const float* src = (arr == 0) ? g1 : g2;
        const int c0 = khalf * 32;

        u32 hw[16], lw[16];
        #pragma unroll
        for (int cc = 0; cc < 32; cc += 2) {
            const int c = c0 + cc;
            float x0 = src[(size_t)c * N + row];
            float x1 = src[(size_t)(c + 1) * N + row];
            if (arr >= 2) {
                x0 *= W[(arr - 2) * CDIM + c];
                x1 *= W[(arr - 2) * CDIM + c + 1];
            }
            unsigned short h0 = bf16_rne(x0), h1 = bf16_rne(x1);
            float hf0 = __uint_as_float((u32)h0 << 16);
            float hf1 = __uint_as_float((u32)h1 << 16);
            unsigned short l0 = bf16_rne(x0 - hf0), l1 = bf16_rne(x1 - hf1);
            hw[cc >> 1] = (u32)h0 | ((u32)h1 << 16);
            lw[cc >> 1] = (u32)l0 | ((u32)l1 << 16);
        }
        // row layout: elems 0..63 = hi(c), 64..127 = lo(c); row stride 128 elems
        unsigned short* rowp = ws_bf + ((size_t)arr << 17) + (size_t)row * 128;
        u4* hi_p = (u4*)(rowp + khalf * 32);
        u4* lo_p = (u4*)(rowp + 64 + khalf * 32);
        #pragma unroll
        for (int q = 0; q < 4; ++q) {
            hi_p[q] = *(u4*)&hw[q * 4];
            lo_p[q] = *(u4*)&lw[q * 4];
        }
    } else {
        const int tid = (b - 32) * 256 + t;    // 0..2047
        const int row = tid & 1023;
        const float* src = (tid < 1024) ? g1 : g2;
        float ss = 0.f;
        #pragma unroll
        for (int c = 0; c < CDIM; ++c) {
            float x = src[(size_t)c * N + row];
            ss = fmaf(x, x, ss);
        }
        float inv = 1.0f / (EPSN + sqrtf(ss));
        float* sc = ws_sc + ((tid < 1024) ? 0 : 2048);   // s[1024], r[1024]
        sc[row]        = ss * inv * inv;
        sc[1024 + row] = inv;
    }
}

// ---------------- main: one wave -> 32x16 output tile -----------------------
__global__ __launch_bounds__(64)
void match_kernel(const unsigned short* __restrict__ ws_bf,
                  const float* __restrict__ ws_sc,
                  const float* __restrict__ bias,
                  float* __restrict__ out, float* __restrict__ onorm, int N) {
    const int l  = threadIdx.x;
    const int m  = l & 15;       // row-within-tile for A, col for B/C
    const int kg = l >> 4;       // k-group
    const int j0 = blockIdx.x * 16;
    const int i0 = blockIdx.y * 32;

    // ---- fragment loads (all from L2-resident ws; slot order consistent A/B)
    s8 Ah[2][2], Al[2][2];                     // [i-tile][k-half]
    #pragma unroll
    for (int it = 0; it < 2; ++it)
        #pragma unroll
        for (int kh = 0; kh < 2; ++kh) {
            const unsigned short* rp =
                ws_bf + (size_t)(i0 + it * 16 + m) * 128 + kh * 32 + kg * 8;
            Ah[it][kh] = *(const s8*)rp;
            Al[it][kh] = *(const s8*)(rp + 64);
        }
    s8 Bh[3][2], Bl[3][2];                     // [variant][k-half]
    #pragma unroll
    for (int v = 0; v < 3; ++v)
        #pragma unroll
        for (int kh = 0; kh < 2; ++kh) {
            const unsigned short* rp =
                ws_bf + ((size_t)(v + 1) << 17) +
                (size_t)(j0 + m) * 128 + kh * 32 + kg * 8;
            Bh[v][kh] = *(const s8*)rp;
            Bl[v][kh] = *(const s8*)(rp + 64);
        }

    const float b0 = bias[0], b1 = bias[1];
    f4 acc[2][3];                              // [i-tile][variant: d,w0,w1]
    #pragma unroll
    for (int it = 0; it < 2; ++it) {
        acc[it][0] = (f4){0.f, 0.f, 0.f, 0.f};
        acc[it][1] = (f4){b0, b0, b0, b0};
        acc[it][2] = (f4){b1, b1, b1, b1};
    }

    // ---- 36 MFMAs: 2 i-tiles x 3 variants x 2 k-halves x 3 split terms
    #pragma unroll
    for (int it = 0; it < 2; ++it)
        #pragma unroll
        for (int v = 0; v < 3; ++v)
            #pragma unroll
            for (int kh = 0; kh < 2; ++kh) {
                acc[it][v] = __builtin_amdgcn_mfma_f32_16x16x32_bf16(
                    Ah[it][kh], Bh[v][kh], acc[it][v], 0, 0, 0);
                acc[it][v] = __builtin_amdgcn_mfma_f32_16x16x32_bf16(
                    Ah[it][kh], Bl[v][kh], acc[it][v], 0, 0, 0);
                acc[it][v] = __builtin_amdgcn_mfma_f32_16x16x32_bf16(
                    Al[it][kh], Bh[v][kh], acc[it][v], 0, 0, 0);
            }

    // ---- epilogue: C layout col = lane&15, row = kg*4 + p (m89-verified)
    const float* s1 = ws_sc;
    const float* r1 = ws_sc + 1024;
    const float* s2 = ws_sc + 2048;
    const float* r2 = ws_sc + 3072;

    const float s2v = s2[j0 + m];
    const float r2v = r2[j0 + m] * -2.0f;

    #pragma unroll
    for (int it = 0; it < 2; ++it) {
        const int rbase = i0 + it * 16 + kg * 4;
        const f4 s1v = *(const f4*)&s1[rbase];
        const f4 r1v = *(const f4*)&r1[rbase];
        #pragma unroll
        for (int p = 0; p < 4; ++p) {
            const int row = rbase + p;
            const float dd = acc[it][0][p];
            const float d2 = fmaf(dd * r1v[p], r2v, s1v[p] + s2v);
            const float dn = sqrtf(fmaxf(d2, 0.0f));
            const size_t off = (size_t)row * N + (j0 + m);
            f2 o; o[0] = acc[it][1][p]; o[1] = acc[it][2][p];
            *(f2*)&out[off * 2] = o;
            onorm[off] = dn;
        }
    }
}

extern "C" void kernel_launch(void* const* d_in, const int* in_sizes, int n_in,
                              void* d_out, int out_size, void* d_ws, size_t ws_size,
                              hipStream_t stream) {
    const float* g1   = (const float*)d_in[0];
    const float* g2   = (const float*)d_in[1];
    const float* W    = (const float*)d_in[2];
    const float* bias = (const float*)d_in[3];

    const int N = in_sizes[0] / CDIM;                  // 1024
    float* out   = (float*)d_out;                      // [N*N, 2]
    float* onorm = out + (size_t)2 * N * N;            // [N, N]

    unsigned short* ws_bf = (unsigned short*)d_ws;     // 4 x [1024][128] bf16 = 1 MB
    float*          ws_sc = (float*)((char*)d_ws + (1 << 20));  // s1,r1,s2,r2

    prep_kernel<<<40, 256, 0, stream>>>(g1, g2, W, ws_bf, ws_sc, N);
    dim3 grid(N / 16, N / 32);                         // (64, 32) = 2048 blocks
    match_kernel<<<grid, 64, 0, stream>>>(ws_bf, ws_sc, bias, out, onorm, N);
}

// Round 4
// 12.184 us; speedup vs baseline: 1.5387x; 1.5387x over previous
//
#include <hip/hip_runtime.h>
#include <math.h>

// DescriptorMatcher, fully fused single dispatch. b=1, c=64, N=1024.
//   out[i,j,o] = sum_c v1[i,c]*v2[j,c]*W[o,c] + bias[o]
//   onorm[i,j] = sqrt(s1[i] + s2[j] - 2*dot(i,j)*r1[i]*r2[j])
// One 64-thread (1-wave) block computes a 32x16 output tile:
//   - gather fp32 A-rows/B-col fragments straight from L2-resident inputs
//   - split-bf16 (hi+lo) conversion in-register (rel err ~2^-17)
//   - norm sums in fp32 via __shfl_xor butterfly over the 4 k-groups
//   - 36x mfma_f32_16x16x32_bf16 (3 GEMM variants x 2 k-halves x 3 split terms)
//   - epilogue row-scalars redistributed with __shfl
// No LDS, no barriers, no workspace, one dispatch. 2048 waves = 8/CU.

#define CDIM 64
#define EPSN 1e-6f

typedef float        f4  __attribute__((ext_vector_type(4)));
typedef float        f2  __attribute__((ext_vector_type(2)));
typedef short        s8v __attribute__((ext_vector_type(8)));
typedef unsigned int u32;

__device__ __forceinline__ unsigned short bf16_rne(float x) {
    u32 u = __float_as_uint(x);
    u32 r = u + 0x7fffu + ((u >> 16) & 1u);
    return (unsigned short)(r >> 16);
}

__device__ __forceinline__ void split2(float x, short& h, short& lo) {
    unsigned short hh = bf16_rne(x);
    float hf = __uint_as_float((u32)hh << 16);
    h  = (short)hh;
    lo = (short)bf16_rne(x - hf);
}

__global__ __launch_bounds__(64, 2)
void fused_kernel(const float* __restrict__ g1, const float* __restrict__ g2,
                  const float* __restrict__ W, const float* __restrict__ bias,
                  float* __restrict__ out, float* __restrict__ onorm, int N) {
    const int l  = threadIdx.x;
    const int m  = l & 15;       // A-row / B-col / C-col within tile
    const int kg = l >> 4;       // k-group
    const int j0 = blockIdx.x * 16;
    const int i0 = blockIdx.y * 32;
    const int cb = kg * 8;       // k-slot base within each 32-wide k-half

    // ---- raw fp32 gathers (inputs are 512 KB total -> L2/L3-resident)
    float xa[2][2][8];   // v1: [it][kh][q], row = i0+it*16+m, c = kh*32+cb+q
    float xb[2][8];      // v2: [kh][q],    col = j0+m
    #pragma unroll
    for (int it = 0; it < 2; ++it)
        #pragma unroll
        for (int kh = 0; kh < 2; ++kh)
            #pragma unroll
            for (int q = 0; q < 8; ++q)
                xa[it][kh][q] =
                    g1[(size_t)(kh * 32 + cb + q) * N + (i0 + it * 16 + m)];
    #pragma unroll
    for (int kh = 0; kh < 2; ++kh)
        #pragma unroll
        for (int q = 0; q < 8; ++q)
            xb[kh][q] = g2[(size_t)(kh * 32 + cb + q) * N + (j0 + m)];

    float wv[2][2][8];   // W[o][kh*32+cb+q]
    #pragma unroll
    for (int o = 0; o < 2; ++o)
        #pragma unroll
        for (int kh = 0; kh < 2; ++kh) {
            *(f4*)&wv[o][kh][0] = *(const f4*)&W[o * CDIM + kh * 32 + cb];
            *(f4*)&wv[o][kh][4] = *(const f4*)&W[o * CDIM + kh * 32 + cb + 4];
        }

    // ---- norm sums (exact fp32): partial over this lane's 16 c's, then
    //      butterfly across the 4 kg-groups (lanes sharing m)
    float ss1[2] = {0.f, 0.f}, ss2 = 0.f;
    #pragma unroll
    for (int it = 0; it < 2; ++it)
        #pragma unroll
        for (int kh = 0; kh < 2; ++kh)
            #pragma unroll
            for (int q = 0; q < 8; ++q)
                ss1[it] = fmaf(xa[it][kh][q], xa[it][kh][q], ss1[it]);
    #pragma unroll
    for (int kh = 0; kh < 2; ++kh)
        #pragma unroll
        for (int q = 0; q < 8; ++q)
            ss2 = fmaf(xb[kh][q], xb[kh][q], ss2);

    #pragma unroll
    for (int it = 0; it < 2; ++it) {
        ss1[it] += __shfl_xor(ss1[it], 16);
        ss1[it] += __shfl_xor(ss1[it], 32);
    }
    ss2 += __shfl_xor(ss2, 16);
    ss2 += __shfl_xor(ss2, 32);

    float r1x[2], s1x[2];
    #pragma unroll
    for (int it = 0; it < 2; ++it) {
        float inv = 1.0f / (EPSN + sqrtf(ss1[it]));
        r1x[it] = inv;
        s1x[it] = ss1[it] * inv * inv;
    }
    const float r2  = 1.0f / (EPSN + sqrtf(ss2));
    const float s2e = ss2 * r2 * r2;
    const float r2m = r2 * -2.0f;

    // ---- build split-bf16 fragments in-register
    s8v Ah[2][2], Al[2][2];
    #pragma unroll
    for (int it = 0; it < 2; ++it)
        #pragma unroll
        for (int kh = 0; kh < 2; ++kh)
            #pragma unroll
            for (int q = 0; q < 8; ++q) {
                short h, lo; split2(xa[it][kh][q], h, lo);
                Ah[it][kh][q] = h; Al[it][kh][q] = lo;
            }
    s8v Bh[3][2], Bl[3][2];   // variants: 0=plain, 1=*w0, 2=*w1
    #pragma unroll
    for (int kh = 0; kh < 2; ++kh)
        #pragma unroll
        for (int q = 0; q < 8; ++q) {
            float x = xb[kh][q];
            short h, lo;
            split2(x, h, lo);                 Bh[0][kh][q] = h; Bl[0][kh][q] = lo;
            split2(x * wv[0][kh][q], h, lo);  Bh[1][kh][q] = h; Bl[1][kh][q] = lo;
            split2(x * wv[1][kh][q], h, lo);  Bh[2][kh][q] = h; Bl[2][kh][q] = lo;
        }

    const float b0 = bias[0], b1 = bias[1];
    f4 acc[2][3];             // [it][variant: dot, out0, out1]
    #pragma unroll
    for (int it = 0; it < 2; ++it) {
        acc[it][0] = (f4){0.f, 0.f, 0.f, 0.f};
        acc[it][1] = (f4){b0, b0, b0, b0};
        acc[it][2] = (f4){b1, b1, b1, b1};
    }

    // ---- 36 MFMAs: hi*hi + hi*lo + lo*hi per (it, variant, k-half)
    #pragma unroll
    for (int it = 0; it < 2; ++it)
        #pragma unroll
        for (int v = 0; v < 3; ++v)
            #pragma unroll
            for (int kh = 0; kh < 2; ++kh) {
                acc[it][v] = __builtin_amdgcn_mfma_f32_16x16x32_bf16(
                    Ah[it][kh], Bh[v][kh], acc[it][v], 0, 0, 0);
                acc[it][v] = __builtin_amdgcn_mfma_f32_16x16x32_bf16(
                    Ah[it][kh], Bl[v][kh], acc[it][v], 0, 0, 0);
                acc[it][v] = __builtin_amdgcn_mfma_f32_16x16x32_bf16(
                    Al[it][kh], Bh[v][kh], acc[it][v], 0, 0, 0);
            }

    // ---- epilogue: C layout col = m, row = kg*4 + p; row-scalars held by
    //      lane (m' = kg*4+p) -> pull with __shfl
    #pragma unroll
    for (int it = 0; it < 2; ++it)
        #pragma unroll
        for (int p = 0; p < 4; ++p) {
            const int rsel = kg * 4 + p;               // lane holding this row
            const float s1e = __shfl(s1x[it], rsel);
            const float r1e = __shfl(r1x[it], rsel);
            const int row = i0 + it * 16 + rsel;
            const float dd = acc[it][0][p];
            const float d2 = fmaf(dd * r1e, r2m, s1e + s2e);
            const float dn = sqrtf(fmaxf(d2, 0.0f));
            const size_t off = (size_t)row * N + (j0 + m);
            f2 o; o[0] = acc[it][1][p]; o[1] = acc[it][2][p];
            *(f2*)&out[off * 2] = o;
            onorm[off] = dn;
        }
}

extern "C" void kernel_launch(void* const* d_in, const int* in_sizes, int n_in,
                              void* d_out, int out_size, void* d_ws, size_t ws_size,
                              hipStream_t stream) {
    const float* g1   = (const float*)d_in[0];
    const float* g2   = (const float*)d_in[1];
    const float* W    = (const float*)d_in[2];
    const float* bias = (const float*)d_in[3];

    const int N = in_sizes[0] / CDIM;              // 1024
    float* out   = (float*)d_out;                  // [N*N, 2]
    float* onorm = out + (size_t)2 * N * N;        // [N, N]

    dim3 grid(N / 16, N / 32);                     // (64, 32) = 2048 blocks
    fused_kernel<<<grid, 64, 0, stream>>>(g1, g2, W, bias, out, onorm, N);
}

// Round 5
// 11.906 us; speedup vs baseline: 1.5746x; 1.0233x over previous
//
#include <hip/hip_runtime.h>
#include <hip/hip_bf16.h>
#include <math.h>

// DescriptorMatcher, fully fused single dispatch. b=1, c=64, N=1024.
//   out[i,j,o] = sum_c v1[i,c]*v2[j,c]*W[o,c] + bias[o]
//   onorm[i,j] = sqrt(s1[i] + s2[j] - 2*dot(i,j)*r1[i]*r2[j])
// One 64-thread (1-wave) block computes a 16x16 output tile:
//   - gather fp32 fragments from L2-resident inputs
//   - split-bf16 (hi+lo) via native casts (v_cvt_pk_bf16_f32)
//   - norm sums via __shfl_xor butterfly over the 4 k-groups
//   - 18x mfma_f32_16x16x32_bf16 (3 variants x 2 k-halves x 3 split terms)
//   - epilogue row-scalars redistributed with __shfl
// 4096 blocks = 16 waves/CU, __launch_bounds__(64,4) for 4 waves/SIMD.

#define CDIM 64
#define EPSN 1e-6f

typedef float        f4  __attribute__((ext_vector_type(4)));
typedef float        f2  __attribute__((ext_vector_type(2)));
typedef short        s8v __attribute__((ext_vector_type(8)));
typedef unsigned int u32;

__device__ __forceinline__ void split2(float x, short& h, short& lo) {
    __hip_bfloat16 hb = __float2bfloat16(x);          // RNE, cvt_pk-fusable
    float hf = __bfloat162float(hb);
    __hip_bfloat16 lb = __float2bfloat16(x - hf);
    h  = (short)__bfloat16_as_ushort(hb);
    lo = (short)__bfloat16_as_ushort(lb);
}

__global__ __launch_bounds__(64, 4)
void fused_kernel(const float* __restrict__ g1, const float* __restrict__ g2,
                  const float* __restrict__ W, const float* __restrict__ bias,
                  float* __restrict__ out, float* __restrict__ onorm, int N) {
    const int l  = threadIdx.x;
    const int m  = l & 15;       // A-row / B-col / C-col within tile
    const int kg = l >> 4;       // k-group
    const int j0 = blockIdx.x * 16;
    const int i0 = blockIdx.y * 16;
    const int cb = kg * 8;       // k-slot base within each 32-wide k-half

    // ---- raw fp32 gathers (inputs 512 KB -> L2-resident)
    float xa[2][8], xb[2][8];    // [kh][q]; A row = i0+m, B col = j0+m
    #pragma unroll
    for (int kh = 0; kh < 2; ++kh)
        #pragma unroll
        for (int q = 0; q < 8; ++q) {
            const size_t coff = (size_t)(kh * 32 + cb + q) * N;
            xa[kh][q] = g1[coff + (i0 + m)];
            xb[kh][q] = g2[coff + (j0 + m)];
        }

    float wv[2][2][8];   // W[o][kh*32+cb+q]
    #pragma unroll
    for (int o = 0; o < 2; ++o)
        #pragma unroll
        for (int kh = 0; kh < 2; ++kh) {
            *(f4*)&wv[o][kh][0] = *(const f4*)&W[o * CDIM + kh * 32 + cb];
            *(f4*)&wv[o][kh][4] = *(const f4*)&W[o * CDIM + kh * 32 + cb + 4];
        }

    // ---- norm sums (fp32 exact): lane partial (16 c's) + butterfly over kg
    float ss1 = 0.f, ss2 = 0.f;
    #pragma unroll
    for (int kh = 0; kh < 2; ++kh)
        #pragma unroll
        for (int q = 0; q < 8; ++q) {
            ss1 = fmaf(xa[kh][q], xa[kh][q], ss1);
            ss2 = fmaf(xb[kh][q], xb[kh][q], ss2);
        }
    ss1 += __shfl_xor(ss1, 16);  ss1 += __shfl_xor(ss1, 32);
    ss2 += __shfl_xor(ss2, 16);  ss2 += __shfl_xor(ss2, 32);

    const float r1  = 1.0f / (EPSN + sqrtf(ss1));
    const float s1e = ss1 * r1 * r1;
    const float r2  = 1.0f / (EPSN + sqrtf(ss2));
    const float s2e = ss2 * r2 * r2;
    const float r2m = r2 * -2.0f;

    // ---- split-bf16 fragments in-register
    s8v Ah[2], Al[2];
    #pragma unroll
    for (int kh = 0; kh < 2; ++kh)
        #pragma unroll
        for (int q = 0; q < 8; ++q) {
            short h, lo; split2(xa[kh][q], h, lo);
            Ah[kh][q] = h; Al[kh][q] = lo;
        }
    s8v Bh[3][2], Bl[3][2];      // variants: 0=plain, 1=*w0, 2=*w1
    #pragma unroll
    for (int kh = 0; kh < 2; ++kh)
        #pragma unroll
        for (int q = 0; q < 8; ++q) {
            float x = xb[kh][q];
            short h, lo;
            split2(x, h, lo);                 Bh[0][kh][q] = h; Bl[0][kh][q] = lo;
            split2(x * wv[0][kh][q], h, lo);  Bh[1][kh][q] = h; Bl[1][kh][q] = lo;
            split2(x * wv[1][kh][q], h, lo);  Bh[2][kh][q] = h; Bl[2][kh][q] = lo;
        }

    const float b0 = bias[0], b1 = bias[1];
    f4 acc[3];                   // [variant: dot, out0, out1]
    acc[0] = (f4){0.f, 0.f, 0.f, 0.f};
    acc[1] = (f4){b0, b0, b0, b0};
    acc[2] = (f4){b1, b1, b1, b1};

    // ---- 18 MFMAs: hi*hi + hi*lo + lo*hi per (variant, k-half)
    #pragma unroll
    for (int v = 0; v < 3; ++v)
        #pragma unroll
        for (int kh = 0; kh < 2; ++kh) {
            acc[v] = __builtin_amdgcn_mfma_f32_16x16x32_bf16(
                Ah[kh], Bh[v][kh], acc[v], 0, 0, 0);
            acc[v] = __builtin_amdgcn_mfma_f32_16x16x32_bf16(
                Ah[kh], Bl[v][kh], acc[v], 0, 0, 0);
            acc[v] = __builtin_amdgcn_mfma_f32_16x16x32_bf16(
                Al[kh], Bh[v][kh], acc[v], 0, 0, 0);
        }

    // ---- epilogue: C layout col = m, row = kg*4 + p; row-scalars pulled by shfl
    #pragma unroll
    for (int p = 0; p < 4; ++p) {
        const int rsel = kg * 4 + p;           // lane holding this row's scalars
        const float s1r = __shfl(s1e, rsel);
        const float r1r = __shfl(r1, rsel);
        const int row = i0 + rsel;
        const float dd = acc[0][p];
        const float d2 = fmaf(dd * r1r, r2m, s1r + s2e);
        const float dn = sqrtf(fmaxf(d2, 0.0f));
        const size_t off = (size_t)row * N + (j0 + m);
        f2 o; o[0] = acc[1][p]; o[1] = acc[2][p];
        *(f2*)&out[off * 2] = o;
        onorm[off] = dn;
    }
}

extern "C" void kernel_launch(void* const* d_in, const int* in_sizes, int n_in,
                              void* d_out, int out_size, void* d_ws, size_t ws_size,
                              hipStream_t stream) {
    const float* g1   = (const float*)d_in[0];
    const float* g2   = (const float*)d_in[1];
    const float* W    = (const float*)d_in[2];
    const float* bias = (const float*)d_in[3];

    const int N = in_sizes[0] / CDIM;              // 1024
    float* out   = (float*)d_out;                  // [N*N, 2]
    float* onorm = out + (size_t)2 * N * N;        // [N, N]

    dim3 grid(N / 16, N / 16);                     // 64 x 64 = 4096 blocks
    fused_kernel<<<grid, 64, 0, stream>>>(g1, g2, W, bias, out, onorm, N);
}

// Round 6
// 10.521 us; speedup vs baseline: 1.7820x; 1.1317x over previous
//
#include <hip/hip_runtime.h>
#include <hip/hip_bf16.h>
#include <math.h>

// DescriptorMatcher, fully fused single dispatch. b=1, c=64, N=1024.
//   out[i,j,o] = sum_c v1[i,c]*v2[j,c]*W[o,c] + bias[o]
//   onorm[i,j] = sqrt(s1[i] + s2[j] - 2*dot(i,j)*r1[i]*r2[j])
// One 64-thread (1-wave) block computes a 16x16 output tile.
// Precision scheme (threshold 0.13):
//   - plain dot: 2-term split  Ah*(Bh+Bl)  -> dot err ~0.02, damped by
//     2*r1*r2 (~1/32) in d^2 -> ~0.001; dn err at cancellation ~0.03.
//   - W-variants: hi-only Ah*Bh -> |W|~0.125-damped err ~0.004-0.05.
//   => 8 MFMAs total, no A-lo fragments.
// Non-temporal stores: outputs are streamed (12.6 MB), never re-read.
// 4096 blocks = 4 waves/SIMD, no LDS, no barriers, single dispatch.

#define CDIM 64
#define EPSN 1e-6f

typedef float        f4  __attribute__((ext_vector_type(4)));
typedef float        f2  __attribute__((ext_vector_type(2)));
typedef short        s8v __attribute__((ext_vector_type(8)));
typedef unsigned int u32;

__device__ __forceinline__ short bf16_hi(float x) {
    return (short)__bfloat16_as_ushort(__float2bfloat16(x));
}

__global__ __launch_bounds__(64, 4)
void fused_kernel(const float* __restrict__ g1, const float* __restrict__ g2,
                  const float* __restrict__ W, const float* __restrict__ bias,
                  float* __restrict__ out, float* __restrict__ onorm, int N) {
    const int l  = threadIdx.x;
    const int m  = l & 15;       // A-row / B-col / C-col within tile
    const int kg = l >> 4;       // k-group
    const int j0 = blockIdx.x * 16;
    const int i0 = blockIdx.y * 16;
    const int cb = kg * 8;       // k-slot base within each 32-wide k-half

    // ---- raw fp32 gathers (inputs 512 KB -> L2-resident)
    float xa[2][8], xb[2][8];    // [kh][q]; A row = i0+m, B col = j0+m
    #pragma unroll
    for (int kh = 0; kh < 2; ++kh)
        #pragma unroll
        for (int q = 0; q < 8; ++q) {
            const size_t coff = (size_t)(kh * 32 + cb + q) * N;
            xa[kh][q] = g1[coff + (i0 + m)];
            xb[kh][q] = g2[coff + (j0 + m)];
        }

    float wv[2][2][8];   // W[o][kh*32+cb+q]
    #pragma unroll
    for (int o = 0; o < 2; ++o)
        #pragma unroll
        for (int kh = 0; kh < 2; ++kh) {
            *(f4*)&wv[o][kh][0] = *(const f4*)&W[o * CDIM + kh * 32 + cb];
            *(f4*)&wv[o][kh][4] = *(const f4*)&W[o * CDIM + kh * 32 + cb + 4];
        }

    // ---- norm sums (fp32 exact): lane partial (16 c's) + butterfly over kg
    float ss1 = 0.f, ss2 = 0.f;
    #pragma unroll
    for (int kh = 0; kh < 2; ++kh)
        #pragma unroll
        for (int q = 0; q < 8; ++q) {
            ss1 = fmaf(xa[kh][q], xa[kh][q], ss1);
            ss2 = fmaf(xb[kh][q], xb[kh][q], ss2);
        }
    ss1 += __shfl_xor(ss1, 16);  ss1 += __shfl_xor(ss1, 32);
    ss2 += __shfl_xor(ss2, 16);  ss2 += __shfl_xor(ss2, 32);

    const float r1  = 1.0f / (EPSN + sqrtf(ss1));
    const float s1e = ss1 * r1 * r1;
    const float r2  = 1.0f / (EPSN + sqrtf(ss2));
    const float s2e = ss2 * r2 * r2;
    const float r2m = r2 * -2.0f;

    // ---- bf16 fragments in-register (A: hi only; B: hi+lo; Bw0/Bw1: hi only)
    s8v Ah[2], Bh[2], Bl[2], Bw0[2], Bw1[2];
    #pragma unroll
    for (int kh = 0; kh < 2; ++kh)
        #pragma unroll
        for (int q = 0; q < 8; ++q) {
            Ah[kh][q] = bf16_hi(xa[kh][q]);
            float x = xb[kh][q];
            short h = bf16_hi(x);
            Bh[kh][q] = h;
            Bl[kh][q] = bf16_hi(x - __bfloat162float(__ushort_as_bfloat16((unsigned short)h)));
            Bw0[kh][q] = bf16_hi(x * wv[0][kh][q]);
            Bw1[kh][q] = bf16_hi(x * wv[1][kh][q]);
        }

    const float b0 = bias[0], b1 = bias[1];
    f4 acc[3];                   // [variant: dot, out0, out1]
    acc[0] = (f4){0.f, 0.f, 0.f, 0.f};
    acc[1] = (f4){b0, b0, b0, b0};
    acc[2] = (f4){b1, b1, b1, b1};

    // ---- 8 MFMAs
    #pragma unroll
    for (int kh = 0; kh < 2; ++kh) {
        acc[0] = __builtin_amdgcn_mfma_f32_16x16x32_bf16(Ah[kh], Bh[kh],  acc[0], 0, 0, 0);
        acc[0] = __builtin_amdgcn_mfma_f32_16x16x32_bf16(Ah[kh], Bl[kh],  acc[0], 0, 0, 0);
        acc[1] = __builtin_amdgcn_mfma_f32_16x16x32_bf16(Ah[kh], Bw0[kh], acc[1], 0, 0, 0);
        acc[2] = __builtin_amdgcn_mfma_f32_16x16x32_bf16(Ah[kh], Bw1[kh], acc[2], 0, 0, 0);
    }

    // ---- epilogue: C layout col = m, row = kg*4 + p; row scalars via shfl
    #pragma unroll
    for (int p = 0; p < 4; ++p) {
        const int rsel = kg * 4 + p;           // lane holding this row's scalars
        const float s1r = __shfl(s1e, rsel);
        const float r1r = __shfl(r1, rsel);
        const int row = i0 + rsel;
        const float dd = acc[0][p];
        const float d2 = fmaf(dd * r1r, r2m, s1r + s2e);
        const float dn = sqrtf(fmaxf(d2, 0.0f));
        const size_t off = (size_t)row * N + (j0 + m);
        f2 o; o[0] = acc[1][p]; o[1] = acc[2][p];
        __builtin_nontemporal_store(o,  (f2*)&out[off * 2]);
        __builtin_nontemporal_store(dn, &onorm[off]);
    }
}

extern "C" void kernel_launch(void* const* d_in, const int* in_sizes, int n_in,
                              void* d_out, int out_size, void* d_ws, size_t ws_size,
                              hipStream_t stream) {
    const float* g1   = (const float*)d_in[0];
    const float* g2   = (const float*)d_in[1];
    const float* W    = (const float*)d_in[2];
    const float* bias = (const float*)d_in[3];

    const int N = in_sizes[0] / CDIM;              // 1024
    float* out   = (float*)d_out;                  // [N*N, 2]
    float* onorm = out + (size_t)2 * N * N;        // [N, N]

    dim3 grid(N / 16, N / 16);                     // 64 x 64 = 4096 blocks
    fused_kernel<<<grid, 64, 0, stream>>>(g1, g2, W, bias, out, onorm, N);
}